// Round 17
// baseline (163.846 us; speedup 1.0000x reference)
//
#include <hip/hip_runtime.h>
#include <hip/hip_bf16.h>
#include <math.h>

#define T_TOK  16384
#define H_DIM  512
#define NHEADS 12
#define E_DIM  768
#define EPS_N  1e-5f
#define QK_SCALE 0.04419417382415922f

typedef unsigned short u16;
typedef __bf16 bf16;
typedef bf16   bf16x8 __attribute__((ext_vector_type(8)));
typedef float  f32x4  __attribute__((ext_vector_type(4)));
typedef u16    u16x4  __attribute__((ext_vector_type(4)));
typedef u16    u16x8  __attribute__((ext_vector_type(8)));

__device__ __forceinline__ u16 f2bf(float f) {
  unsigned u = __builtin_bit_cast(unsigned, f);
  unsigned r = u + 0x7fffu + ((u >> 16) & 1u);
  return (u16)(r >> 16);
}
__device__ __forceinline__ float bf2f(u16 h) {
  unsigned u = ((unsigned)h) << 16;
  return __builtin_bit_cast(float, u);
}

// ---------------- Kernel A: merged prep (gather + wcat + wc/qwkw) -----------
__global__ __launch_bounds__(256) void prep_all(
    const int* __restrict__ hash_ids, const int* __restrict__ offsets,
    const float* __restrict__ emb_w, u16* __restrict__ emb,
    const float* __restrict__ kp, const float* __restrict__ vp,
    u16* __restrict__ wt,
    const float* __restrict__ conv_w, const float* __restrict__ cnw,
    const float* __restrict__ qw, const float* __restrict__ kw,
    float* __restrict__ wc, float* __restrict__ qwkw) {
  __shared__ float tile[32][33];
  int b = blockIdx.x, tid = threadIdx.x;
  if (b < 6144) {
    int idx = b * 256 + tid;                       // T*12*8
    int pair = idx >> 3;
    int sub = idx & 7;
    int t = pair / 12;
    int head = pair - t * 12;
    int row = hash_ids[pair] + offsets[head];
    const float* src = emb_w + (size_t)row * 64 + sub * 8;
    float4 a = *(const float4*)src;
    float4 c = *(const float4*)(src + 4);
    u16x8 o;
    o[0] = f2bf(a.x); o[1] = f2bf(a.y); o[2] = f2bf(a.z); o[3] = f2bf(a.w);
    o[4] = f2bf(c.x); o[5] = f2bf(c.y); o[6] = f2bf(c.z); o[7] = f2bf(c.w);
    *(u16x8*)(emb + (size_t)t * E_DIM + head * 64 + sub * 8) = o;
  } else if (b < 8064) {
    int i = b - 6144;                              // 0..1919 = 16*24*5
    int m = i / 384;
    int rem = i - m * 384;
    int h0 = (rem & 15) * 32, e0 = (rem >> 4) * 32;
    const float* src = (m < 4) ? (kp + (size_t)m * E_DIM * H_DIM) : vp;
    int tx = tid & 31, ty = tid >> 5;              // (32,8)
    #pragma unroll
    for (int j = 0; j < 32; j += 8)
      tile[ty + j][tx] = src[(size_t)(e0 + ty + j) * H_DIM + h0 + tx];
    __syncthreads();
    #pragma unroll
    for (int j = 0; j < 32; j += 8) {
      int h = h0 + ty + j, e = e0 + tx;
      wt[(size_t)(m * H_DIM + h) * E_DIM + e] = f2bf(tile[tx][ty + j]);
    }
  } else {
    #pragma unroll
    for (int c8 = 0; c8 < 8; ++c8) {
      int cf = c8 * 256 + tid;                     // 2048
      float c = cnw[cf];
      #pragma unroll
      for (int k = 0; k < 4; ++k) wc[k * 2048 + cf] = conv_w[cf * 4 + k] * c;
      qwkw[cf] = qw[cf] * kw[cf];
    }
  }
}

// ---------------- Kernel B: GEMM + fully fused gate-side epilogue -----------
// r13 structure with the epilogue qlds shrunk to [128][128] via the r14-
// verified rank-XOR swizzle -> LDS exactly 32768 -> 5 blocks/CU.
__global__ __launch_bounds__(256, 2) void gemm_bf16(
    const u16* __restrict__ A, const u16* __restrict__ BT,
    const float* __restrict__ hidden, const float* __restrict__ qwkw,
    u16* __restrict__ V, float* __restrict__ kssP, float* __restrict__ qkP,
    float* __restrict__ qssP, float* __restrict__ msvP) {
  __shared__ __align__(16) char smem[32768];
  u16 (*As)[64] = (u16(*)[64])smem;                // [128][64]
  u16 (*Bs)[64] = (u16(*)[64])(smem + 16384);      // [128][64]
  u16*    qlds  = (u16*)smem;                      // [128][128] rank-XOR swz
  float2* red2h = (float2*)smem;                   // [2][128][8] (reused AFTER qlds reads)
  float*  red1  = (float*)smem;                    // [2][128][16] (vraw path)
  const int K = E_DIM;
  int tid = threadIdx.x;
  int lane = tid & 63, wid = tid >> 6;

  // bijective XCD swizzle: 2560 blocks % 8 == 0
  int orig = blockIdx.x + blockIdx.y * 20;
  int swz = (orig & 7) * 320 + (orig >> 3);
  int bx = swz % 20, by = swz / 20;

  int wm = (wid >> 1) * 64, wn = (wid & 1) * 64;
  int widN = wid & 1;
  int lr16 = lane & 15, rgrp = lane >> 4;
  int swz8 = lr16 & 7;

  // staging: pre-swizzled global source unit (involution: unit ^= row&7)
  int srow = tid >> 3;
  int sunit = ((tid & 7) ^ (srow & 7)) * 8;
  const u16* aptr = A + (size_t)(by * 128 + srow) * K + sunit;
  const u16* bptr = BT + (size_t)(bx * 128 + srow) * K + sunit;
  int lds_off = tid * 16;

  f32x4 acc[4][4] = {};

  for (int k0 = 0; k0 < K; k0 += 64) {
    #pragma unroll
    for (int r = 0; r < 4; ++r) {
      __builtin_amdgcn_global_load_lds(
        (const __attribute__((address_space(1))) void*)(aptr + (size_t)(r * 32) * K + k0),
        (__attribute__((address_space(3))) void*)(smem + r * 4096 + lds_off),
        16, 0, 0);
      __builtin_amdgcn_global_load_lds(
        (const __attribute__((address_space(1))) void*)(bptr + (size_t)(r * 32) * K + k0),
        (__attribute__((address_space(3))) void*)(smem + 16384 + r * 4096 + lds_off),
        16, 0, 0);
    }
    __syncthreads();
    #pragma unroll
    for (int kk = 0; kk < 2; ++kk) {
      int un = ((kk * 4 + rgrp) ^ swz8) * 8;       // swizzled unit (elements)
      bf16x8 af[4], bfv[4];
      #pragma unroll
      for (int m = 0; m < 4; ++m)
        af[m] = *reinterpret_cast<const bf16x8*>(&As[wm + m * 16 + lr16][un]);
      #pragma unroll
      for (int n = 0; n < 4; ++n)
        bfv[n] = *reinterpret_cast<const bf16x8*>(&Bs[wn + n * 16 + lr16][un]);
      #pragma unroll
      for (int m = 0; m < 4; ++m)
        #pragma unroll
        for (int n = 0; n < 4; ++n)
          acc[m][n] = __builtin_amdgcn_mfma_f32_16x16x32_bf16(af[m], bfv[n], acc[m][n], 0, 0, 0);
    }
    __syncthreads();
  }
  // K-loop done; all waves past final barrier -> staging LDS reusable.

  if (bx < 16) {
    int g = bx >> 2, qq = bx & 3;
    // ---- stage hidden quarter (128x128 fp32 -> rank-XOR bf16 LDS) + qss ----
    const float* hq = hidden + (size_t)(by * 128) * 2048 + g * 512 + qq * 128;
    int rxw = (((tid >> 4) >> 2) & 3) << 4;        // write-side rank XOR
    float s2[8];
    #pragma unroll
    for (int p = 0; p < 8; ++p) {
      int row = p * 16 + (tid >> 4);
      int col = (tid & 15) * 8;
      const float* src = hq + (size_t)row * 2048 + col;
      float4 x0 = *(const float4*)src;
      float4 x1 = *(const float4*)(src + 4);
      float qv[8] = {x0.x, x0.y, x0.z, x0.w, x1.x, x1.y, x1.z, x1.w};
      u16x8 o;
      float ss = 0.f;
      #pragma unroll
      for (int j = 0; j < 8; ++j) { ss += qv[j] * qv[j]; o[j] = f2bf(qv[j]); }
      s2[p] = ss;
      *(u16x8*)&qlds[row * 128 + (col ^ rxw)] = o;
    }
    #pragma unroll
    for (int off = 1; off < 16; off <<= 1)
      #pragma unroll
      for (int p = 0; p < 8; ++p) s2[p] += __shfl_xor(s2[p], off, 64);
    if ((tid & 15) == 0) {
      #pragma unroll
      for (int p = 0; p < 8; ++p) {
        int t = by * 128 + p * 16 + (tid >> 4);
        qssP[(t * 4 + g) * 4 + qq] = s2[p];
      }
    }
    __syncthreads();

    // ---- per-thread k-side sums into REGISTERS (qlds still live) ----
    int colg = g * 512 + qq * 128 + wn + lr16;
    float w4[4];
    #pragma unroll
    for (int n = 0; n < 4; ++n) w4[n] = qwkw[colg + n * 16];
    int rxr = rgrp << 4;                           // read-side rank XOR
    float sk2r[16], sqkr[16];
    #pragma unroll
    for (int m = 0; m < 4; ++m) {
      #pragma unroll
      for (int j = 0; j < 4; ++j) {
        int r = wm + m * 16 + rgrp * 4 + j;        // block-local row
        float sk2 = 0.f, sqk = 0.f;
        #pragma unroll
        for (int n = 0; n < 4; ++n) {
          float kv = acc[m][n][j];
          float qv = bf2f(qlds[r * 128 + ((wn + n * 16 + lr16) ^ rxr)]);
          sk2 += kv * kv;
          sqk += qv * w4[n] * kv;
        }
        sk2 += __shfl_xor(sk2, 8, 64);
        sqk += __shfl_xor(sqk, 8, 64);
        sk2r[m * 4 + j] = sk2;
        sqkr[m * 4 + j] = sqk;
      }
    }
    __syncthreads();                               // all qlds reads done
    // ---- spill register sums into reused LDS, transpose-reduce ----
    if (lr16 < 8) {
      #pragma unroll
      for (int m = 0; m < 4; ++m)
        #pragma unroll
        for (int j = 0; j < 4; ++j) {
          int r = wm + m * 16 + rgrp * 4 + j;
          red2h[(widN * 128 + r) * 8 + lr16] =
              make_float2(sk2r[m * 4 + j], sqkr[m * 4 + j]);
        }
    }
    __syncthreads();
    if (tid < 128) {
      float s0 = 0.f, s1 = 0.f;
      #pragma unroll
      for (int j = 0; j < 8; ++j) {
        int jj = (j + tid) & 7;
        float2 a = red2h[tid * 8 + jj];
        float2 b = red2h[(128 + tid) * 8 + jj];
        s0 += a.x + b.x;
        s1 += a.y + b.y;
      }
      int t = by * 128 + tid;
      int o = (t * 4 + g) * 4 + qq;
      kssP[o] = s0;
      qkP[o]  = s1;
    }
  } else {
    // ---- vraw tile: store bf16 V + per-row v^2 via LDS transpose ----
    int q2i = bx - 16;
    #pragma unroll
    for (int m = 0; m < 4; ++m) {
      #pragma unroll
      for (int j = 0; j < 4; ++j) {
        int r = wm + m * 16 + rgrp * 4 + j;
        size_t t = (size_t)(by * 128 + r);
        float sv2 = 0.f;
        #pragma unroll
        for (int n = 0; n < 4; ++n) {
          float v = acc[m][n][j];
          sv2 += v * v;
          V[t * 512 + q2i * 128 + wn + n * 16 + lr16] = f2bf(v);
        }
        red1[(widN * 128 + r) * 16 + lr16] = sv2;
      }
    }
    __syncthreads();
    if (tid < 128) {
      float s = 0.f;
      #pragma unroll
      for (int j = 0; j < 16; ++j) {
        int jj = (j + tid) & 15;
        s += red1[tid * 16 + jj] + red1[(128 + tid) * 16 + jj];
      }
      int t = by * 128 + tid;
      msvP[t * 4 + q2i] = s;
    }
  }
}

// ---------------- Kernel C: gates + value + dilated conv + silu + out -------
__global__ __launch_bounds__(256) void out_kernel(
    const u16* __restrict__ V,          // (T,512) bf16
    const float* __restrict__ kssP, const float* __restrict__ qkP,
    const float* __restrict__ qssP, const float* __restrict__ msvP,
    const float* __restrict__ wc,       // [4][2048]
    float* __restrict__ out) {
  __shared__ float aL[4][4];            // [tap][g]
  __shared__ float gL[4];               // gate for t, per g
  int t = blockIdx.x;
  int tid = threadIdx.x;
  int c8 = tid * 8;
  int g = c8 >> 9;
  int h = c8 & 511;

  // ---- all threads: independent V-tap + wc register loads ----
  u16x8 vv[4];
  float w8[4][8];
  #pragma unroll
  for (int k = 0; k < 4; ++k) {
    int tk = t - 12 + 4 * k;
    if (tk >= 0) vv[k] = *(const u16x8*)&V[(size_t)tk * 512 + h];
    float4 w0 = *(const float4*)(wc + k * 2048 + c8);
    float4 w1 = *(const float4*)(wc + k * 2048 + c8 + 4);
    w8[k][0] = w0.x; w8[k][1] = w0.y; w8[k][2] = w0.z; w8[k][3] = w0.w;
    w8[k][4] = w1.x; w8[k][5] = w1.y; w8[k][6] = w1.z; w8[k][7] = w1.w;
  }

  // ---- threads 0-15: scalar gate/a for the 4 taps (overlaps loads above) --
  if (tid < 16) {
    int k = tid >> 2, gg = tid & 3;
    int tk = t - 12 + 4 * k;
    if (tk >= 0) {
      int i = tk * 4 + gg;
      float4 k4 = *(const float4*)&kssP[i * 4];
      float4 d4 = *(const float4*)&qkP[i * 4];
      float4 q4 = *(const float4*)&qssP[i * 4];
      float4 m4 = *(const float4*)&msvP[tk * 4];
      float kss = k4.x + k4.y + k4.z + k4.w;
      float qk  = d4.x + d4.y + d4.z + d4.w;
      float qss = q4.x + q4.y + q4.z + q4.w;
      float msv = (m4.x + m4.y + m4.z + m4.w) * (1.0f / 512.0f);
      float qinv = rsqrtf(qss * (1.0f / 512.0f) + EPS_N);
      float kinv = rsqrtf(kss * (1.0f / 512.0f) + EPS_N);
      float gate = 1.0f / (1.0f + __expf(-qk * qinv * kinv * QK_SCALE));
      aL[k][gg] = gate * rsqrtf(gate * gate * msv + EPS_N);
      if (k == 3) gL[gg] = gate;
    } else {
      aL[k][gg] = 0.f;
    }
  }
  __syncthreads();

  // ---- combine ----
  float acc[8] = {0.f, 0.f, 0.f, 0.f, 0.f, 0.f, 0.f, 0.f};
  float vr_t[8];
  #pragma unroll
  for (int k = 0; k < 4; ++k) {
    int tk = t - 12 + 4 * k;
    if (tk < 0) continue;
    float s = aL[k][g];
    #pragma unroll
    for (int j = 0; j < 8; ++j) {
      float v = bf2f(vv[k][j]);
      acc[j] += w8[k][j] * s * v;
      if (k == 3) vr_t[j] = v;
    }
  }
  float gate = gL[g];
  float r[8];
  #pragma unroll
  for (int j = 0; j < 8; ++j) {
    float y = acc[j];
    r[j] = gate * vr_t[j] + y / (1.0f + __expf(-y));
  }
  float* op = out + (size_t)t * 2048 + c8;
  *(float4*)op       = make_float4(r[0], r[1], r[2], r[3]);
  *(float4*)(op + 4) = make_float4(r[4], r[5], r[6], r[7]);
}

extern "C" void kernel_launch(void* const* d_in, const int* in_sizes, int n_in,
                              void* d_out, int out_size, void* d_ws, size_t ws_size,
                              hipStream_t stream) {
  const int*   hash_ids = (const int*)d_in[0];
  const int*   offsets  = (const int*)d_in[1];
  const float* emb_w    = (const float*)d_in[2];
  const float* kp       = (const float*)d_in[3];
  const float* qw       = (const float*)d_in[4];
  const float* kw       = (const float*)d_in[5];
  const float* vp       = (const float*)d_in[6];
  const float* conv_w   = (const float*)d_in[7];
  const float* cw       = (const float*)d_in[8];
  const float* hidden   = (const float*)d_in[9];
  float* out = (float*)d_out;
  char*  ws  = (char*)d_ws;

  u16*   V     = (u16*)ws;                       // 16,777,216
  u16*   emb   = (u16*)(ws + 16777216);          // 25,165,824
  u16*   wt    = (u16*)(ws + 41943040);          //  3,932,160
  float* kssP  = (float*)(ws + 45875200);        //  1,048,576
  float* qkP   = (float*)(ws + 46923776);        //  1,048,576
  float* qssP  = (float*)(ws + 47972352);        //  1,048,576
  float* msvP  = (float*)(ws + 49020928);        //    262,144
  float* wc    = (float*)(ws + 49283072);        //     32,768
  float* qwkw  = (float*)(ws + 49315840);        //      8,192

  prep_all<<<8065, 256, 0, stream>>>(hash_ids, offsets, emb_w, emb,
                                     kp, vp, wt, conv_w, cw, qw, kw, wc, qwkw);
  gemm_bf16<<<dim3(20, 128), 256, 0, stream>>>(emb, wt, hidden, qwkw,
                                               V, kssP, qkP, qssP, msvP);
  out_kernel<<<T_TOK, 256, 0, stream>>>(V, kssP, qkP, qssP, msvP, wc, out);
}

// Round 18
// 160.183 us; speedup vs baseline: 1.0229x; 1.0229x over previous
//
#include <hip/hip_runtime.h>
#include <hip/hip_bf16.h>
#include <math.h>

#define T_TOK  16384
#define H_DIM  512
#define NHEADS 12
#define E_DIM  768
#define EPS_N  1e-5f
#define QK_SCALE 0.04419417382415922f

typedef unsigned short u16;
typedef __bf16 bf16;
typedef bf16   bf16x8 __attribute__((ext_vector_type(8)));
typedef float  f32x4  __attribute__((ext_vector_type(4)));
typedef u16    u16x4  __attribute__((ext_vector_type(4)));
typedef u16    u16x8  __attribute__((ext_vector_type(8)));

__device__ __forceinline__ u16 f2bf(float f) {
  unsigned u = __builtin_bit_cast(unsigned, f);
  unsigned r = u + 0x7fffu + ((u >> 16) & 1u);
  return (u16)(r >> 16);
}
__device__ __forceinline__ float bf2f(u16 h) {
  unsigned u = ((unsigned)h) << 16;
  return __builtin_bit_cast(float, u);
}

// ---------------- Kernel A: merged prep (gather + wcat + wc/qwkw) -----------
__global__ __launch_bounds__(256) void prep_all(
    const int* __restrict__ hash_ids, const int* __restrict__ offsets,
    const float* __restrict__ emb_w, u16* __restrict__ emb,
    const float* __restrict__ kp, const float* __restrict__ vp,
    u16* __restrict__ wt,
    const float* __restrict__ conv_w, const float* __restrict__ cnw,
    const float* __restrict__ qw, const float* __restrict__ kw,
    float* __restrict__ wc, float* __restrict__ qwkw) {
  __shared__ float tile[32][33];
  int b = blockIdx.x, tid = threadIdx.x;
  if (b < 6144) {
    int idx = b * 256 + tid;                       // T*12*8
    int pair = idx >> 3;
    int sub = idx & 7;
    int t = pair / 12;
    int head = pair - t * 12;
    int row = hash_ids[pair] + offsets[head];
    const float* src = emb_w + (size_t)row * 64 + sub * 8;
    float4 a = *(const float4*)src;
    float4 c = *(const float4*)(src + 4);
    u16x8 o;
    o[0] = f2bf(a.x); o[1] = f2bf(a.y); o[2] = f2bf(a.z); o[3] = f2bf(a.w);
    o[4] = f2bf(c.x); o[5] = f2bf(c.y); o[6] = f2bf(c.z); o[7] = f2bf(c.w);
    *(u16x8*)(emb + (size_t)t * E_DIM + head * 64 + sub * 8) = o;
  } else if (b < 8064) {
    int i = b - 6144;                              // 0..1919 = 16*24*5
    int m = i / 384;
    int rem = i - m * 384;
    int h0 = (rem & 15) * 32, e0 = (rem >> 4) * 32;
    const float* src = (m < 4) ? (kp + (size_t)m * E_DIM * H_DIM) : vp;
    int tx = tid & 31, ty = tid >> 5;              // (32,8)
    #pragma unroll
    for (int j = 0; j < 32; j += 8)
      tile[ty + j][tx] = src[(size_t)(e0 + ty + j) * H_DIM + h0 + tx];
    __syncthreads();
    #pragma unroll
    for (int j = 0; j < 32; j += 8) {
      int h = h0 + ty + j, e = e0 + tx;
      wt[(size_t)(m * H_DIM + h) * E_DIM + e] = f2bf(tile[tx][ty + j]);
    }
  } else {
    #pragma unroll
    for (int c8 = 0; c8 < 8; ++c8) {
      int cf = c8 * 256 + tid;                     // 2048
      float c = cnw[cf];
      #pragma unroll
      for (int k = 0; k < 4; ++k) wc[k * 2048 + cf] = conv_w[cf * 4 + k] * c;
      qwkw[cf] = qw[cf] * kw[cf];
    }
  }
}

// ---------------- Kernel B: GEMM + fully fused gate-side epilogue -----------
// (r13/r16 structure: 128^2 tile, both-sides XOR swizzle, register-buffered
// epilogue reduction reusing qlds as transpose scratch; LDS 33792, VGPR ~76.)
__global__ __launch_bounds__(256, 2) void gemm_bf16(
    const u16* __restrict__ A, const u16* __restrict__ BT,
    const float* __restrict__ hidden, const float* __restrict__ qwkw,
    u16* __restrict__ V, float* __restrict__ kssP, float* __restrict__ qkP,
    float* __restrict__ qssP, float* __restrict__ msvP) {
  __shared__ __align__(16) char smem[33792];
  u16 (*As)[64] = (u16(*)[64])smem;                // [128][64]
  u16 (*Bs)[64] = (u16(*)[64])(smem + 16384);      // [128][64]
  u16*    qlds  = (u16*)smem;                      // [128][132] bf16 (epilogue)
  float2* red2h = (float2*)smem;                   // [2][128][8] (reused AFTER qlds reads)
  float*  red1  = (float*)smem;                    // [2][128][16] (vraw path)
  const int K = E_DIM;
  int tid = threadIdx.x;
  int lane = tid & 63, wid = tid >> 6;

  // bijective XCD swizzle: 2560 blocks % 8 == 0
  int orig = blockIdx.x + blockIdx.y * 20;
  int swz = (orig & 7) * 320 + (orig >> 3);
  int bx = swz % 20, by = swz / 20;

  int wm = (wid >> 1) * 64, wn = (wid & 1) * 64;
  int widN = wid & 1;
  int lr16 = lane & 15, rgrp = lane >> 4;
  int swz8 = lr16 & 7;

  // staging: pre-swizzled global source unit (involution: unit ^= row&7)
  int srow = tid >> 3;
  int sunit = ((tid & 7) ^ (srow & 7)) * 8;
  const u16* aptr = A + (size_t)(by * 128 + srow) * K + sunit;
  const u16* bptr = BT + (size_t)(bx * 128 + srow) * K + sunit;
  int lds_off = tid * 16;

  f32x4 acc[4][4] = {};

  for (int k0 = 0; k0 < K; k0 += 64) {
    #pragma unroll
    for (int r = 0; r < 4; ++r) {
      __builtin_amdgcn_global_load_lds(
        (const __attribute__((address_space(1))) void*)(aptr + (size_t)(r * 32) * K + k0),
        (__attribute__((address_space(3))) void*)(smem + r * 4096 + lds_off),
        16, 0, 0);
      __builtin_amdgcn_global_load_lds(
        (const __attribute__((address_space(1))) void*)(bptr + (size_t)(r * 32) * K + k0),
        (__attribute__((address_space(3))) void*)(smem + 16384 + r * 4096 + lds_off),
        16, 0, 0);
    }
    __syncthreads();
    #pragma unroll
    for (int kk = 0; kk < 2; ++kk) {
      int un = ((kk * 4 + rgrp) ^ swz8) * 8;       // swizzled unit (elements)
      bf16x8 af[4], bfv[4];
      #pragma unroll
      for (int m = 0; m < 4; ++m)
        af[m] = *reinterpret_cast<const bf16x8*>(&As[wm + m * 16 + lr16][un]);
      #pragma unroll
      for (int n = 0; n < 4; ++n)
        bfv[n] = *reinterpret_cast<const bf16x8*>(&Bs[wn + n * 16 + lr16][un]);
      #pragma unroll
      for (int m = 0; m < 4; ++m)
        #pragma unroll
        for (int n = 0; n < 4; ++n)
          acc[m][n] = __builtin_amdgcn_mfma_f32_16x16x32_bf16(af[m], bfv[n], acc[m][n], 0, 0, 0);
    }
    __syncthreads();
  }
  // K-loop done; all waves past final barrier -> staging LDS reusable.

  if (bx < 16) {
    int g = bx >> 2, qq = bx & 3;
    // ---- stage hidden quarter (128x128 fp32 -> bf16 LDS), qss on the fly ---
    const float* hq = hidden + (size_t)(by * 128) * 2048 + g * 512 + qq * 128;
    float s2[8];
    #pragma unroll
    for (int p = 0; p < 8; ++p) {
      int row = p * 16 + (tid >> 4);
      int col = (tid & 15) * 8;
      const float* src = hq + (size_t)row * 2048 + col;
      float4 x0 = *(const float4*)src;
      float4 x1 = *(const float4*)(src + 4);
      float qv[8] = {x0.x, x0.y, x0.z, x0.w, x1.x, x1.y, x1.z, x1.w};
      u16x8 o;
      float ss = 0.f;
      #pragma unroll
      for (int j = 0; j < 8; ++j) { ss += qv[j] * qv[j]; o[j] = f2bf(qv[j]); }
      s2[p] = ss;
      *(u16x8*)&qlds[row * 132 + col] = o;
    }
    #pragma unroll
    for (int off = 1; off < 16; off <<= 1)
      #pragma unroll
      for (int p = 0; p < 8; ++p) s2[p] += __shfl_xor(s2[p], off, 64);
    if ((tid & 15) == 0) {
      #pragma unroll
      for (int p = 0; p < 8; ++p) {
        int t = by * 128 + p * 16 + (tid >> 4);
        qssP[(t * 4 + g) * 4 + qq] = s2[p];
      }
    }
    __syncthreads();

    // ---- per-thread k-side sums into REGISTERS (qlds still live) ----
    int colg = g * 512 + qq * 128 + wn + lr16;
    float w4[4];
    #pragma unroll
    for (int n = 0; n < 4; ++n) w4[n] = qwkw[colg + n * 16];
    float sk2r[16], sqkr[16];
    #pragma unroll
    for (int m = 0; m < 4; ++m) {
      #pragma unroll
      for (int j = 0; j < 4; ++j) {
        int r = wm + m * 16 + rgrp * 4 + j;        // block-local row
        float sk2 = 0.f, sqk = 0.f;
        #pragma unroll
        for (int n = 0; n < 4; ++n) {
          float kv = acc[m][n][j];
          float qv = bf2f(qlds[r * 132 + wn + n * 16 + lr16]);
          sk2 += kv * kv;
          sqk += qv * w4[n] * kv;
        }
        sk2 += __shfl_xor(sk2, 8, 64);
        sqk += __shfl_xor(sqk, 8, 64);
        sk2r[m * 4 + j] = sk2;
        sqkr[m * 4 + j] = sqk;
      }
    }
    __syncthreads();                               // all qlds reads done
    // ---- spill register sums into reused LDS, transpose-reduce ----
    if (lr16 < 8) {
      #pragma unroll
      for (int m = 0; m < 4; ++m)
        #pragma unroll
        for (int j = 0; j < 4; ++j) {
          int r = wm + m * 16 + rgrp * 4 + j;
          red2h[(widN * 128 + r) * 8 + lr16] =
              make_float2(sk2r[m * 4 + j], sqkr[m * 4 + j]);
        }
    }
    __syncthreads();
    if (tid < 128) {
      float s0 = 0.f, s1 = 0.f;
      #pragma unroll
      for (int j = 0; j < 8; ++j) {
        int jj = (j + tid) & 7;
        float2 a = red2h[tid * 8 + jj];
        float2 b = red2h[(128 + tid) * 8 + jj];
        s0 += a.x + b.x;
        s1 += a.y + b.y;
      }
      int t = by * 128 + tid;
      int o = (t * 4 + g) * 4 + qq;
      kssP[o] = s0;
      qkP[o]  = s1;
    }
  } else {
    // ---- vraw tile: store bf16 V + per-row v^2 via LDS transpose ----
    int q2i = bx - 16;
    #pragma unroll
    for (int m = 0; m < 4; ++m) {
      #pragma unroll
      for (int j = 0; j < 4; ++j) {
        int r = wm + m * 16 + rgrp * 4 + j;
        size_t t = (size_t)(by * 128 + r);
        float sv2 = 0.f;
        #pragma unroll
        for (int n = 0; n < 4; ++n) {
          float v = acc[m][n][j];
          sv2 += v * v;
          V[t * 512 + q2i * 128 + wn + n * 16 + lr16] = f2bf(v);
        }
        red1[(widN * 128 + r) * 16 + lr16] = sv2;
      }
    }
    __syncthreads();
    if (tid < 128) {
      float s = 0.f;
      #pragma unroll
      for (int j = 0; j < 16; ++j) {
        int jj = (j + tid) & 15;
        s += red1[tid * 16 + jj] + red1[(128 + tid) * 16 + jj];
      }
      int t = by * 128 + tid;
      msvP[t * 4 + q2i] = s;
    }
  }
}

// ---------------- Kernel C: gates + value + dilated conv + silu + out -------
__global__ __launch_bounds__(256) void out_kernel(
    const u16* __restrict__ V,          // (T,512) bf16
    const float* __restrict__ kssP, const float* __restrict__ qkP,
    const float* __restrict__ qssP, const float* __restrict__ msvP,
    const float* __restrict__ wc,       // [4][2048]
    float* __restrict__ out) {
  __shared__ float aL[4][4];            // [tap][g]
  __shared__ float gL[4];               // gate for t, per g
  int t = blockIdx.x;
  int tid = threadIdx.x;
  int c8 = tid * 8;
  int g = c8 >> 9;
  int h = c8 & 511;

  // ---- all threads: independent V-tap + wc register loads ----
  u16x8 vv[4];
  float w8[4][8];
  #pragma unroll
  for (int k = 0; k < 4; ++k) {
    int tk = t - 12 + 4 * k;
    if (tk >= 0) vv[k] = *(const u16x8*)&V[(size_t)tk * 512 + h];
    float4 w0 = *(const float4*)(wc + k * 2048 + c8);
    float4 w1 = *(const float4*)(wc + k * 2048 + c8 + 4);
    w8[k][0] = w0.x; w8[k][1] = w0.y; w8[k][2] = w0.z; w8[k][3] = w0.w;
    w8[k][4] = w1.x; w8[k][5] = w1.y; w8[k][6] = w1.z; w8[k][7] = w1.w;
  }

  // ---- threads 0-15: scalar gate/a for the 4 taps (overlaps loads above) --
  if (tid < 16) {
    int k = tid >> 2, gg = tid & 3;
    int tk = t - 12 + 4 * k;
    if (tk >= 0) {
      int i = tk * 4 + gg;
      float4 k4 = *(const float4*)&kssP[i * 4];
      float4 d4 = *(const float4*)&qkP[i * 4];
      float4 q4 = *(const float4*)&qssP[i * 4];
      float4 m4 = *(const float4*)&msvP[tk * 4];
      float kss = k4.x + k4.y + k4.z + k4.w;
      float qk  = d4.x + d4.y + d4.z + d4.w;
      float qss = q4.x + q4.y + q4.z + q4.w;
      float msv = (m4.x + m4.y + m4.z + m4.w) * (1.0f / 512.0f);
      float qinv = rsqrtf(qss * (1.0f / 512.0f) + EPS_N);
      float kinv = rsqrtf(kss * (1.0f / 512.0f) + EPS_N);
      float gate = 1.0f / (1.0f + __expf(-qk * qinv * kinv * QK_SCALE));
      aL[k][gg] = gate * rsqrtf(gate * gate * msv + EPS_N);
      if (k == 3) gL[gg] = gate;
    } else {
      aL[k][gg] = 0.f;
    }
  }
  __syncthreads();

  // ---- combine ----
  float acc[8] = {0.f, 0.f, 0.f, 0.f, 0.f, 0.f, 0.f, 0.f};
  float vr_t[8];
  #pragma unroll
  for (int k = 0; k < 4; ++k) {
    int tk = t - 12 + 4 * k;
    if (tk < 0) continue;
    float s = aL[k][g];
    #pragma unroll
    for (int j = 0; j < 8; ++j) {
      float v = bf2f(vv[k][j]);
      acc[j] += w8[k][j] * s * v;
      if (k == 3) vr_t[j] = v;
    }
  }
  float gate = gL[g];
  float r[8];
  #pragma unroll
  for (int j = 0; j < 8; ++j) {
    float y = acc[j];
    r[j] = gate * vr_t[j] + y / (1.0f + __expf(-y));
  }
  float* op = out + (size_t)t * 2048 + c8;
  *(float4*)op       = make_float4(r[0], r[1], r[2], r[3]);
  *(float4*)(op + 4) = make_float4(r[4], r[5], r[6], r[7]);
}

extern "C" void kernel_launch(void* const* d_in, const int* in_sizes, int n_in,
                              void* d_out, int out_size, void* d_ws, size_t ws_size,
                              hipStream_t stream) {
  const int*   hash_ids = (const int*)d_in[0];
  const int*   offsets  = (const int*)d_in[1];
  const float* emb_w    = (const float*)d_in[2];
  const float* kp       = (const float*)d_in[3];
  const float* qw       = (const float*)d_in[4];
  const float* kw       = (const float*)d_in[5];
  const float* vp       = (const float*)d_in[6];
  const float* conv_w   = (const float*)d_in[7];
  const float* cw       = (const float*)d_in[8];
  const float* hidden   = (const float*)d_in[9];
  float* out = (float*)d_out;
  char*  ws  = (char*)d_ws;

  u16*   V     = (u16*)ws;                       // 16,777,216
  u16*   emb   = (u16*)(ws + 16777216);          // 25,165,824
  u16*   wt    = (u16*)(ws + 41943040);          //  3,932,160
  float* kssP  = (float*)(ws + 45875200);        //  1,048,576
  float* qkP   = (float*)(ws + 46923776);        //  1,048,576
  float* qssP  = (float*)(ws + 47972352);        //  1,048,576
  float* msvP  = (float*)(ws + 49020928);        //    262,144
  float* wc    = (float*)(ws + 49283072);        //     32,768
  float* qwkw  = (float*)(ws + 49315840);        //      8,192

  prep_all<<<8065, 256, 0, stream>>>(hash_ids, offsets, emb_w, emb,
                                     kp, vp, wt, conv_w, cw, qw, kw, wc, qwkw);
  gemm_bf16<<<dim3(20, 128), 256, 0, stream>>>(emb, wt, hidden, qwkw,
                                               V, kssP, qkP, qssP, msvP);
  out_kernel<<<T_TOK, 256, 0, stream>>>(V, kssP, qkP, qssP, msvP, wc, out);
}